// Round 10
// baseline (821.541 us; speedup 1.0000x reference)
//
#include <hip/hip_runtime.h>
#include <hip/hip_fp16.h>
#include <hip/hip_cooperative_groups.h>

namespace cg = cooperative_groups;

// GCN 3-layer, single cooperative kernel. Phases separated by grid.sync():
//  0: zero packed
//  A: edge atomics (wave 0 of each block) || GEMM1 MFMA tiles (waves 1-3)
//     || W2/W3 fp32->fp16 convert  -- true same-CU overlap of atomic wall
//     (~35us) and MFMA work, impossible with dispatch-ordered block ranges.
//  B: per-stripe count sums + dis = rsqrt(1+wdeg)   C: scan -> row_ptr
//  D: CSR fill (atomic-free: slot = row_ptr[dest] + rank)
//  E/G/I: aggregation (fp16 gather, fp32 accum, fused bias/BN/ReLU)
//  F/H: GEMM2/GEMM3 (MFMA f16 16x16x32, wave = 16 nodes x F)
// Aggregation layout: thread=(node, 16B chunk) -> 12 lanes share one 192B
// row (~2 line-touches/edge, minimal; R8 lesson).

constexpr float BN_EPS = 1e-5f;
constexpr float FIXED_SCALE = 33554432.0f;        // 2^25 (weighted degree accum)
constexpr float INV_FIXED_SCALE = 1.0f / 33554432.0f;
constexpr float NORM_SCALE = 32768.0f;            // 2^15 (edge norm quant)
constexpr float INV_NORM_SCALE = 1.0f / 32768.0f;

typedef _Float16 f16x8 __attribute__((ext_vector_type(8)));
typedef float f32x4 __attribute__((ext_vector_type(4)));

struct P {
    const int* col_idx; const int* row_idx; const float* ew;
    const float* x; const float* W1; const float* W2; const float* W3;
    const float* b1; const float* g1; const float* be1; const float* m1; const float* v1;
    const float* b2; const float* g2; const float* be2; const float* m2; const float* v2;
    const float* b3;
    unsigned long long* packed;
    int* rank; int* row_ptr; int* bsum;
    float* dis; unsigned* ep;
    _Float16* w2h; _Float16* w3h; _Float16* bufA; _Float16* bufB;
    float* out;
    int N, E, NB;
};

// ---------------- MFMA GEMM wave tile ----------------
// Y[n][f] = sum_k X[n][k]*W[f][k]; one wave computes 16 nodes x F features.
// A: lane loads X[n0+(lane&15)][kt*32+(lane>>4)*8..+7]; C/D: col=lane&15,
// row=(lane>>4)*4+reg.

template <int K, int F, bool F32X, bool F32W>
__device__ __forceinline__ void gemm_wave(const void* __restrict__ Xin,
                                          const void* __restrict__ Win,
                                          _Float16* __restrict__ Y,
                                          int n0, int lane, int n) {
    constexpr int KT = K / 32;
    constexpr int FT = F / 16;
    if (n0 >= n) return;
    int quad = lane >> 4;
    int r = lane & 15;

    f16x8 a[KT];
    if (F32X) {
        const float* xr = (const float*)Xin + (size_t)(n0 + r) * K + quad * 8;
#pragma unroll
        for (int kt = 0; kt < KT; ++kt) {
            float4 v0 = *(const float4*)(xr + kt * 32);
            float4 v1 = *(const float4*)(xr + kt * 32 + 4);
            f16x8 t = {(_Float16)v0.x, (_Float16)v0.y, (_Float16)v0.z, (_Float16)v0.w,
                       (_Float16)v1.x, (_Float16)v1.y, (_Float16)v1.z, (_Float16)v1.w};
            a[kt] = t;
        }
    } else {
        const f16x8* xr = (const f16x8*)((const _Float16*)Xin + (size_t)(n0 + r) * K + quad * 8);
#pragma unroll
        for (int kt = 0; kt < KT; ++kt) a[kt] = xr[kt * 4];
    }

    f32x4 acc[FT];
#pragma unroll
    for (int ft = 0; ft < FT; ++ft) acc[ft] = (f32x4){0.f, 0.f, 0.f, 0.f};

#pragma unroll
    for (int kt = 0; kt < KT; ++kt) {
#pragma unroll
        for (int ft = 0; ft < FT; ++ft) {
            f16x8 b;
            if (F32W) {
                const float* wr = (const float*)Win + (size_t)(ft * 16 + r) * K + kt * 32 + quad * 8;
                float4 v0 = *(const float4*)wr;
                float4 v1 = *(const float4*)(wr + 4);
                f16x8 t = {(_Float16)v0.x, (_Float16)v0.y, (_Float16)v0.z, (_Float16)v0.w,
                           (_Float16)v1.x, (_Float16)v1.y, (_Float16)v1.z, (_Float16)v1.w};
                b = t;
            } else {
                b = *(const f16x8*)((const _Float16*)Win + (size_t)(ft * 16 + r) * K + kt * 32 + quad * 8);
            }
            acc[ft] = __builtin_amdgcn_mfma_f32_16x16x32_f16(a[kt], b, acc[ft], 0, 0, 0);
        }
    }

#pragma unroll
    for (int ft = 0; ft < FT; ++ft) {
#pragma unroll
        for (int reg = 0; reg < 4; ++reg) {
            int row = n0 + quad * 4 + reg;
            Y[(size_t)row * F + ft * 16 + r] = (_Float16)acc[ft][reg];
        }
    }
}

// ---------------- aggregation helpers ----------------

__device__ inline void cvt8(uint4 u, float* f) {
    float2 t;
    t = __half22float2(*(const __half2*)&u.x); f[0] = t.x; f[1] = t.y;
    t = __half22float2(*(const __half2*)&u.y); f[2] = t.x; f[3] = t.y;
    t = __half22float2(*(const __half2*)&u.z); f[4] = t.x; f[5] = t.y;
    t = __half22float2(*(const __half2*)&u.w); f[6] = t.x; f[7] = t.y;
}

__device__ inline void h8_acc(uint4 u, float w, float acc[8]) {
    float2 a = __half22float2(*(const __half2*)&u.x);
    float2 b = __half22float2(*(const __half2*)&u.y);
    float2 c = __half22float2(*(const __half2*)&u.z);
    float2 d = __half22float2(*(const __half2*)&u.w);
    acc[0] = fmaf(w, a.x, acc[0]); acc[1] = fmaf(w, a.y, acc[1]);
    acc[2] = fmaf(w, b.x, acc[2]); acc[3] = fmaf(w, b.y, acc[3]);
    acc[4] = fmaf(w, c.x, acc[4]); acc[5] = fmaf(w, c.y, acc[5]);
    acc[6] = fmaf(w, d.x, acc[6]); acc[7] = fmaf(w, d.y, acc[7]);
}

// thread = (node, 8-half chunk); FQ lanes of one node read one contiguous row.
template <int F, bool BN, bool F32OUT>
__device__ void aggr_phase(const _Float16* __restrict__ xw,
                           const int* __restrict__ row_ptr,
                           const unsigned* __restrict__ ep,
                           const float* __restrict__ dis,
                           const float* __restrict__ bias,
                           const float* __restrict__ g, const float* __restrict__ beta,
                           const float* __restrict__ m, const float* __restrict__ v,
                           void* __restrict__ out, int n, int tid, int gsz) {
    constexpr int FQ = F / 8;
    const uint4* __restrict__ base = (const uint4*)xw;
    int total = n * FQ;
    for (int it = tid; it < total; it += gsz) {
        int node = it / FQ;
        int q = it - node * FQ;

        float acc[8];
        {
            float d = dis[node];
            float d2 = d * d;
            uint4 sv = base[(size_t)node * FQ + q];
            float t[8];
            cvt8(sv, t);
#pragma unroll
            for (int j = 0; j < 8; ++j) acc[j] = d2 * t[j];
        }

        int e0 = row_ptr[node], e1 = row_ptr[node + 1];
        int e = e0;
        for (; e + 4 <= e1; e += 4) {
            unsigned p0 = ep[e + 0], p1 = ep[e + 1], p2 = ep[e + 2], p3 = ep[e + 3];
            uint4 x0 = base[(size_t)(p0 >> 16) * FQ + q];
            uint4 x1 = base[(size_t)(p1 >> 16) * FQ + q];
            uint4 x2 = base[(size_t)(p2 >> 16) * FQ + q];
            uint4 x3 = base[(size_t)(p3 >> 16) * FQ + q];
            h8_acc(x0, (float)(p0 & 0xffffu) * INV_NORM_SCALE, acc);
            h8_acc(x1, (float)(p1 & 0xffffu) * INV_NORM_SCALE, acc);
            h8_acc(x2, (float)(p2 & 0xffffu) * INV_NORM_SCALE, acc);
            h8_acc(x3, (float)(p3 & 0xffffu) * INV_NORM_SCALE, acc);
        }
        for (; e < e1; ++e) {
            unsigned p = ep[e];
            uint4 xv = base[(size_t)(p >> 16) * FQ + q];
            h8_acc(xv, (float)(p & 0xffffu) * INV_NORM_SCALE, acc);
        }

        int fb = q * 8;
        const float4* bb = (const float4*)(bias + fb);
        float4 b0 = bb[0], b1 = bb[1];
        acc[0] += b0.x; acc[1] += b0.y; acc[2] += b0.z; acc[3] += b0.w;
        acc[4] += b1.x; acc[5] += b1.y; acc[6] += b1.z; acc[7] += b1.w;
        if (BN) {
#pragma unroll
            for (int j = 0; j < 8; ++j) {
                acc[j] = fmaxf((acc[j] - m[fb + j]) * rsqrtf(v[fb + j] + BN_EPS) * g[fb + j]
                               + beta[fb + j], 0.f);
            }
        }
        if (F32OUT) {
            float* op = (float*)out + (size_t)node * F + fb;
            *(float4*)(op + 0) = make_float4(acc[0], acc[1], acc[2], acc[3]);
            *(float4*)(op + 4) = make_float4(acc[4], acc[5], acc[6], acc[7]);
        } else {
            __half2 h0 = __floats2half2_rn(acc[0], acc[1]);
            __half2 h1 = __floats2half2_rn(acc[2], acc[3]);
            __half2 h2 = __floats2half2_rn(acc[4], acc[5]);
            __half2 h3 = __floats2half2_rn(acc[6], acc[7]);
            uint4 u = make_uint4(*(unsigned*)&h0, *(unsigned*)&h1,
                                 *(unsigned*)&h2, *(unsigned*)&h3);
            ((uint4*)out)[(size_t)node * FQ + q] = u;
        }
    }
}

// ---------------- the single cooperative kernel ----------------

__global__ __launch_bounds__(256, 4) void k_all(P p) {
    cg::grid_group grid = cg::this_grid();
    const int nB = (int)gridDim.x;
    const int gsz = nB * 256;
    const int tid = (int)blockIdx.x * 256 + (int)threadIdx.x;
    const int wave = threadIdx.x >> 6;
    const int lane = threadIdx.x & 63;
    const int tiles = p.N / 16;   // N divisible by 16 (50000)
    constexpr int W2N4 = 96 * 96 / 4, W3N4 = 64 * 96 / 4;

    // phase 0: zero packed
    for (int i = tid; i < p.N; i += gsz) p.packed[i] = 0ull;
    grid.sync();

    // phase A: wave 0 -> edge atomics (+W convert); waves 1-3 -> GEMM1 tiles
    if (wave == 0) {
        int chunk = (p.E + nB - 1) / nB;
        int e0 = (int)blockIdx.x * chunk;
        int e1 = min(e0 + chunk, p.E);
        for (int e = e0 + lane; e < e1; e += 64) {
            int c = p.col_idx[e];
            unsigned wfix = (unsigned)(p.ew[e] * FIXED_SCALE + 0.5f);
            unsigned long long inc = (1ull << 32) | (unsigned long long)wfix;
            unsigned long long old = atomicAdd(&p.packed[c], inc);
            p.rank[e] = (int)(old >> 32);
        }
        int i = (int)blockIdx.x * 64 + lane;   // W2|W3 fp32->fp16, float4 units
        if (i < W2N4 + W3N4) {
            const float* src; _Float16* dst; int o;
            if (i < W2N4) { src = p.W2; dst = p.w2h; o = i; }
            else          { src = p.W3; dst = p.w3h; o = i - W2N4; }
            float4 vv = ((const float4*)src)[o];
            __half2 h0 = __floats2half2_rn(vv.x, vv.y);
            __half2 h1 = __floats2half2_rn(vv.z, vv.w);
            *(uint2*)(dst + (size_t)o * 4) = make_uint2(*(unsigned*)&h0, *(unsigned*)&h1);
        }
    } else {
        for (int t = (int)blockIdx.x * 3 + (wave - 1); t < tiles; t += 3 * nB)
            gemm_wave<128, 96, true, true>(p.x, p.W1, p.bufA, t * 16, lane, p.N);
    }
    grid.sync();

    // phase B: per-stripe count sums + dis
    if ((int)blockIdx.x < p.NB) {
        __shared__ int s1[256];
        int i = (int)blockIdx.x * 256 + (int)threadIdx.x;
        int cnt = 0;
        if (i < p.N) {
            unsigned long long pk = p.packed[i];
            cnt = (int)(pk >> 32);
            float wsum = (float)(unsigned)(pk & 0xffffffffull) * INV_FIXED_SCALE;
            p.dis[i] = rsqrtf(1.0f + wsum);
        }
        s1[threadIdx.x] = cnt;
        __syncthreads();
        for (int off = 128; off > 0; off >>= 1) {
            if ((int)threadIdx.x < off) s1[threadIdx.x] += s1[threadIdx.x + off];
            __syncthreads();
        }
        if (threadIdx.x == 0) p.bsum[blockIdx.x] = s1[0];
    }
    grid.sync();

    // phase C: each active block scans all stripe sums + local scan -> row_ptr
    if ((int)blockIdx.x < p.NB) {
        __shared__ int sb[256];
        __shared__ int s2[256];
        int t = threadIdx.x;
        int bv = (t < p.NB) ? p.bsum[t] : 0;
        sb[t] = bv;
        __syncthreads();
        for (int off = 1; off < 256; off <<= 1) {
            int xx = (t >= off) ? sb[t - off] : 0;
            __syncthreads();
            sb[t] += xx;
            __syncthreads();
        }
        int boff = (blockIdx.x == 0) ? 0 : sb[blockIdx.x - 1];
        int i = (int)blockIdx.x * 256 + t;
        int v = (i < p.N) ? (int)(p.packed[i] >> 32) : 0;
        s2[t] = v;
        __syncthreads();
        for (int off = 1; off < 256; off <<= 1) {
            int xx = (t >= off) ? s2[t - off] : 0;
            __syncthreads();
            s2[t] += xx;
            __syncthreads();
        }
        int ex = s2[t] - v + boff;
        if (i < p.N) p.row_ptr[i] = ex;
        if (i == 0) p.row_ptr[p.N] = p.E;
    }
    grid.sync();

    // phase D: atomic-free CSR fill; record = {src:16 | norm fixed 2^-15:16}
    for (int e = tid; e < p.E; e += gsz) {
        int r = p.row_idx[e];
        int c = p.col_idx[e];
        float nm = p.dis[r] * p.ew[e] * p.dis[c];
        unsigned q = (unsigned)(nm * NORM_SCALE + 0.5f);
        if (q > 65535u) q = 65535u;
        p.ep[p.row_ptr[c] + p.rank[e]] = ((unsigned)r << 16) | q;
    }
    grid.sync();

    // phase E: aggr layer 1 (bufA -> bufB, fp16 out)
    aggr_phase<96, true, false>(p.bufA, p.row_ptr, p.ep, p.dis, p.b1,
                                p.g1, p.be1, p.m1, p.v1, p.bufB, p.N, tid, gsz);
    grid.sync();

    // phase F: GEMM2
    for (int t = (int)blockIdx.x * 4 + wave; t < tiles; t += 4 * nB)
        gemm_wave<96, 96, false, false>(p.bufB, p.w2h, p.bufA, t * 16, lane, p.N);
    grid.sync();

    // phase G: aggr layer 2
    aggr_phase<96, true, false>(p.bufA, p.row_ptr, p.ep, p.dis, p.b2,
                                p.g2, p.be2, p.m2, p.v2, p.bufB, p.N, tid, gsz);
    grid.sync();

    // phase H: GEMM3
    for (int t = (int)blockIdx.x * 4 + wave; t < tiles; t += 4 * nB)
        gemm_wave<96, 64, false, false>(p.bufB, p.w3h, p.bufA, t * 16, lane, p.N);
    grid.sync();

    // phase I: aggr layer 3 -> fp32 d_out
    aggr_phase<64, false, true>(p.bufA, p.row_ptr, p.ep, p.dis, p.b3,
                                nullptr, nullptr, nullptr, nullptr, p.out, p.N, tid, gsz);
}

// ---------------- launch ----------------

extern "C" void kernel_launch(void* const* d_in, const int* in_sizes, int n_in,
                              void* d_out, int out_size, void* d_ws, size_t ws_size,
                              hipStream_t stream) {
    constexpr int IN = 128, H = 96, OUT = 64;

    const int N = in_sizes[0] / IN;   // 50000
    const int E = in_sizes[2];        // 800000

    char* ws = (char*)d_ws;
    size_t off = 0;
    auto alloc = [&](size_t bytes) -> void* {
        void* p = ws + off;
        off = (off + bytes + 255) & ~(size_t)255;
        return p;
    };

    P prm;
    prm.col_idx = (const int*)d_in[1] + E;
    prm.row_idx = (const int*)d_in[1];
    prm.ew  = (const float*)d_in[2];
    prm.x   = (const float*)d_in[0];
    prm.W1  = (const float*)d_in[3];  prm.b1 = (const float*)d_in[4];
    prm.W2  = (const float*)d_in[5];  prm.b2 = (const float*)d_in[6];
    prm.W3  = (const float*)d_in[7];  prm.b3 = (const float*)d_in[8];
    prm.g1  = (const float*)d_in[9];  prm.be1 = (const float*)d_in[10];
    prm.m1  = (const float*)d_in[11]; prm.v1  = (const float*)d_in[12];
    prm.g2  = (const float*)d_in[13]; prm.be2 = (const float*)d_in[14];
    prm.m2  = (const float*)d_in[15]; prm.v2  = (const float*)d_in[16];

    prm.packed  = (unsigned long long*)alloc((size_t)N * 8);
    prm.dis     = (float*)alloc((size_t)N * 4);
    prm.row_ptr = (int*)alloc((size_t)(N + 1) * 4);
    prm.bsum    = (int*)alloc(256 * 4);
    prm.rank    = (int*)alloc((size_t)E * 4);
    prm.ep      = (unsigned*)alloc((size_t)E * 4);
    prm.w2h     = (_Float16*)alloc((size_t)H * H * 2);
    prm.w3h     = (_Float16*)alloc((size_t)OUT * H * 2);
    prm.bufA    = (_Float16*)alloc((size_t)N * H * 2);
    prm.bufB    = (_Float16*)alloc((size_t)N * H * 2);
    prm.out     = (float*)d_out;
    prm.N = N; prm.E = E; prm.NB = (N + 255) / 256;   // 196 (<=256 for scans)
    (void)ws_size; (void)n_in; (void)out_size;

    // co-resident grid: occupancy query x 256 CUs, clamped; launch_bounds(256,4)
    // guarantees >=4 blocks/CU so 1024 is the expected value.
    int perCU = 0;
    if (hipOccupancyMaxActiveBlocksPerMultiprocessor(&perCU, (const void*)k_all, 256, 0)
            != hipSuccess || perCU <= 0)
        perCU = 2;
    long long nb = (long long)perCU * 256;
    if (nb > 1024) nb = 1024;
    if (nb < 256) nb = 256;

    void* args[] = {&prm};
    hipLaunchCooperativeKernel((void*)k_all, dim3((unsigned)nb), dim3(256), args, 0, stream);
}

// Round 11
// 265.134 us; speedup vs baseline: 3.0986x; 3.0986x over previous
//
#include <hip/hip_runtime.h>
#include <hip/hip_fp16.h>

// GCN 3-layer: x -> GCNConv(W1)+BN+ReLU -> GCNConv(W2)+BN+ReLU -> GCNConv(W3)
// CSR built once: 1 u64 atomic/edge -> {count, weighted-degree, in-bucket rank},
// atomic-free fill; edge record u32 {src:16 | norm fixed 2^-15:16}.
// k_mega: INTERLEAVED roles (blockIdx parity) so deg-atomic blocks and GEMM1
// MFMA blocks are co-resident from dispatch 0 -- the GEMM runs under the
// ~35us atomic wall (R9's range-split serialized them; R10's cooperative
// grid.sync version was 3x slower -- grid-wide barriers are ~100us-class).
// GEMMs: MFMA f16 16x16x32, wave = 16 nodes x F, fp32 accum, LDS-staged
// coalesced uint4 epilogue (R9 did 24 scalar 2B stores/lane).
// Aggregation: thread = (node, 16B chunk) -> 12 lanes share one 192B row
// (~2 line-touches/edge, minimal -- R8 lesson).

constexpr float BN_EPS = 1e-5f;
constexpr float FIXED_SCALE = 33554432.0f;        // 2^25 (weighted degree accum)
constexpr float INV_FIXED_SCALE = 1.0f / 33554432.0f;
constexpr float NORM_SCALE = 32768.0f;            // 2^15 (edge norm quant)
constexpr float INV_NORM_SCALE = 1.0f / 32768.0f;

typedef _Float16 f16x8 __attribute__((ext_vector_type(8)));
typedef float f32x4 __attribute__((ext_vector_type(4)));

// ---------------- MFMA GEMM block (64 nodes x F), LDS-staged epilogue ----------
// A: lane loads X[n0+(lane&15)][kt*32+(lane>>4)*8..+7]; C/D: col=lane&15 (f),
// row=(lane>>4)*4+reg (node). LDS row stride padded so 4-row stride is not
// 0 mod 32 banks (104 halves = 52 dw, 4*52=208 % 32 = 16; 72 -> 144 % 32 = 16).

template <int K, int F, bool F32X, bool F32W>
__device__ __forceinline__ void gemm_block(const void* __restrict__ Xin,
                                           const void* __restrict__ Win,
                                           _Float16* __restrict__ Y,
                                           int n0b, int tid, int n,
                                           _Float16* lds) {
    constexpr int KT = K / 32;
    constexpr int FT = F / 16;
    constexpr int LROW = (F == 96) ? 104 : 72;   // padded halves per row
    int wave = tid >> 6;
    int lane = tid & 63;
    int quad = lane >> 4;
    int r = lane & 15;
    int n0 = n0b + wave * 16;
    bool active = (n0 < n);   // N % 16 == 0, so active waves are fully in-bounds

    if (active) {
        f16x8 a[KT];
        if (F32X) {
            const float* xr = (const float*)Xin + (size_t)(n0 + r) * K + quad * 8;
#pragma unroll
            for (int kt = 0; kt < KT; ++kt) {
                float4 v0 = *(const float4*)(xr + kt * 32);
                float4 v1 = *(const float4*)(xr + kt * 32 + 4);
                f16x8 t = {(_Float16)v0.x, (_Float16)v0.y, (_Float16)v0.z, (_Float16)v0.w,
                           (_Float16)v1.x, (_Float16)v1.y, (_Float16)v1.z, (_Float16)v1.w};
                a[kt] = t;
            }
        } else {
            const f16x8* xr = (const f16x8*)((const _Float16*)Xin + (size_t)(n0 + r) * K + quad * 8);
#pragma unroll
            for (int kt = 0; kt < KT; ++kt) a[kt] = xr[kt * 4];
        }

        f32x4 acc[FT];
#pragma unroll
        for (int ft = 0; ft < FT; ++ft) acc[ft] = (f32x4){0.f, 0.f, 0.f, 0.f};

#pragma unroll
        for (int kt = 0; kt < KT; ++kt) {
#pragma unroll
            for (int ft = 0; ft < FT; ++ft) {
                f16x8 b;
                if (F32W) {
                    const float* wr = (const float*)Win + (size_t)(ft * 16 + r) * K + kt * 32 + quad * 8;
                    float4 v0 = *(const float4*)wr;
                    float4 v1 = *(const float4*)(wr + 4);
                    f16x8 t = {(_Float16)v0.x, (_Float16)v0.y, (_Float16)v0.z, (_Float16)v0.w,
                               (_Float16)v1.x, (_Float16)v1.y, (_Float16)v1.z, (_Float16)v1.w};
                    b = t;
                } else {
                    b = *(const f16x8*)((const _Float16*)Win + (size_t)(ft * 16 + r) * K + kt * 32 + quad * 8);
                }
                acc[ft] = __builtin_amdgcn_mfma_f32_16x16x32_f16(a[kt], b, acc[ft], 0, 0, 0);
            }
        }

#pragma unroll
        for (int ft = 0; ft < FT; ++ft) {
#pragma unroll
            for (int reg = 0; reg < 4; ++reg) {
                int lr = wave * 16 + quad * 4 + reg;
                lds[(size_t)lr * LROW + ft * 16 + r] = (_Float16)acc[ft][reg];
            }
        }
    }
    __syncthreads();

    constexpr int CPR = F / 8;            // uint4 chunks per row
    constexpr int TOTAL = 64 * CPR;
    for (int i = tid; i < TOTAL; i += 256) {
        int row = i / CPR, c = i - row * CPR;
        int grow = n0b + row;
        if (grow < n)
            *(uint4*)(Y + (size_t)grow * F + c * 8) =
                *(const uint4*)(lds + (size_t)row * LROW + c * 8);
    }
}

template <int K, int F>
__global__ __launch_bounds__(256) void k_gemm(const _Float16* __restrict__ X,
                                              const _Float16* __restrict__ Wh,
                                              _Float16* __restrict__ Y, int n) {
    __shared__ _Float16 lds[64 * 104];
    gemm_block<K, F, false, false>(X, Wh, Y, blockIdx.x * 64, threadIdx.x, n, lds);
}

// ---------------- mega: interleaved deg atomics | GEMM1 | W2/W3 convert -------

__global__ __launch_bounds__(256) void k_mega(
    const int* __restrict__ col_idx, const float* __restrict__ ew,
    unsigned long long* packed, int* rank, int e_cnt, int pair_b,
    const float* __restrict__ x, const float* __restrict__ W1,
    _Float16* __restrict__ bufA, int n,
    const float* __restrict__ W2, const float* __restrict__ W3,
    _Float16* __restrict__ w2h, _Float16* __restrict__ w3h,
    int w2n4, int w3n4) {
    __shared__ _Float16 lds[64 * 104];
    int b = blockIdx.x;
    if (b < 2 * pair_b) {
        int q = b >> 1;
        if ((b & 1) == 0) {
            // deg role: 1024 edges per block (4 independent atomics/thread)
#pragma unroll
            for (int j = 0; j < 4; ++j) {
                int e = q * 1024 + j * 256 + (int)threadIdx.x;
                if (e < e_cnt) {
                    int c = col_idx[e];
                    unsigned wfix = (unsigned)(ew[e] * FIXED_SCALE + 0.5f);
                    unsigned long long inc = (1ull << 32) | (unsigned long long)wfix;
                    unsigned long long old = atomicAdd(&packed[c], inc);
                    rank[e] = (int)(old >> 32);
                }
            }
        } else {
            gemm_block<128, 96, true, true>(x, W1, bufA, q * 64, threadIdx.x, n, lds);
        }
    } else {
        // convert role: W2|W3 fp32->fp16, 15 blocks x 256 = 3840 float4 units
        int i = (b - 2 * pair_b) * 256 + (int)threadIdx.x;
        const float* src; _Float16* dst; int o;
        if (i < w2n4) { src = W2; dst = w2h; o = i; }
        else if (i < w2n4 + w3n4) { src = W3; dst = w3h; o = i - w2n4; }
        else return;
        float4 v = ((const float4*)src)[o];
        __half2 h0 = __floats2half2_rn(v.x, v.y);
        __half2 h1 = __floats2half2_rn(v.z, v.w);
        *(uint2*)(dst + (size_t)o * 4) = make_uint2(*(unsigned*)&h0, *(unsigned*)&h1);
    }
}

// ---------------- scans ----------------

__global__ void k_scan1(const unsigned long long* __restrict__ packed,
                        int* bsum, float* dis, int n) {
    __shared__ int s[256];
    int i = blockIdx.x * 256 + threadIdx.x;
    int cnt = 0;
    if (i < n) {
        unsigned long long p = packed[i];
        cnt = (int)(p >> 32);
        float wsum = (float)(unsigned)(p & 0xffffffffull) * INV_FIXED_SCALE;
        dis[i] = rsqrtf(1.0f + wsum);   // self-loop weight 1 included
    }
    s[threadIdx.x] = cnt;
    __syncthreads();
    for (int off = 128; off > 0; off >>= 1) {
        if ((int)threadIdx.x < off) s[threadIdx.x] += s[threadIdx.x + off];
        __syncthreads();
    }
    if (threadIdx.x == 0) bsum[blockIdx.x] = s[0];
}

// each block re-scans the stripe sums + local scan -> row_ptr (nb <= 256)
__global__ void k_scan23(const unsigned long long* __restrict__ packed,
                         const int* __restrict__ bsum,
                         int* row_ptr, int n, int e_total, int nb) {
    __shared__ int sb[256];
    __shared__ int s[256];
    int t = threadIdx.x;
    int bv = (t < nb) ? bsum[t] : 0;
    sb[t] = bv;
    __syncthreads();
    for (int off = 1; off < 256; off <<= 1) {
        int x = (t >= off) ? sb[t - off] : 0;
        __syncthreads();
        sb[t] += x;
        __syncthreads();
    }
    int boff = (blockIdx.x == 0) ? 0 : sb[blockIdx.x - 1];

    int i = blockIdx.x * 256 + t;
    int v = (i < n) ? (int)(packed[i] >> 32) : 0;
    s[t] = v;
    __syncthreads();
    for (int off = 1; off < 256; off <<= 1) {
        int x = (t >= off) ? s[t - off] : 0;
        __syncthreads();
        s[t] += x;
        __syncthreads();
    }
    int ex = s[t] - v + boff;
    if (i < n) row_ptr[i] = ex;
    if (i == 0) row_ptr[n] = e_total;
}

// atomic-free fill: slot = row_ptr[dest] + rank; record = {src:16 | norm:16}
__global__ void k_fill(const int* __restrict__ row_idx, const int* __restrict__ col_idx,
                       const float* __restrict__ ew, const float* __restrict__ dis,
                       const int* __restrict__ row_ptr, const int* __restrict__ rank,
                       unsigned* ep, int e_cnt) {
    int e = blockIdx.x * 256 + threadIdx.x;
    if (e < e_cnt) {
        int r = row_idx[e];
        int c = col_idx[e];
        float nm = dis[r] * ew[e] * dis[c];
        unsigned q = (unsigned)(nm * NORM_SCALE + 0.5f);
        if (q > 65535u) q = 65535u;
        ep[row_ptr[c] + rank[e]] = ((unsigned)r << 16) | q;
    }
}

// ---------------- aggregation (gather fp16, accumulate fp32) ----------------

__device__ inline void cvt8(uint4 u, float* f) {
    float2 t;
    t = __half22float2(*(const __half2*)&u.x); f[0] = t.x; f[1] = t.y;
    t = __half22float2(*(const __half2*)&u.y); f[2] = t.x; f[3] = t.y;
    t = __half22float2(*(const __half2*)&u.z); f[4] = t.x; f[5] = t.y;
    t = __half22float2(*(const __half2*)&u.w); f[6] = t.x; f[7] = t.y;
}

__device__ inline void h8_acc(uint4 u, float w, float acc[8]) {
    float2 a = __half22float2(*(const __half2*)&u.x);
    float2 b = __half22float2(*(const __half2*)&u.y);
    float2 c = __half22float2(*(const __half2*)&u.z);
    float2 d = __half22float2(*(const __half2*)&u.w);
    acc[0] = fmaf(w, a.x, acc[0]); acc[1] = fmaf(w, a.y, acc[1]);
    acc[2] = fmaf(w, b.x, acc[2]); acc[3] = fmaf(w, b.y, acc[3]);
    acc[4] = fmaf(w, c.x, acc[4]); acc[5] = fmaf(w, c.y, acc[5]);
    acc[6] = fmaf(w, d.x, acc[6]); acc[7] = fmaf(w, d.y, acc[7]);
}

template <int F, bool BN, bool F32OUT>
__global__ __launch_bounds__(256) void k_aggr(
    const _Float16* __restrict__ xw, const int* __restrict__ row_ptr,
    const unsigned* __restrict__ ep,
    const float* __restrict__ dis, const float* __restrict__ bias,
    const float* __restrict__ g, const float* __restrict__ beta,
    const float* __restrict__ m, const float* __restrict__ v,
    void* __restrict__ out, int n) {
    constexpr int FQ = F / 8;      // 16B chunks per row: 12 (F=96) or 8 (F=64)
    int tg = blockIdx.x * 256 + threadIdx.x;
    int node = tg / FQ;
    int q = tg - node * FQ;
    if (node >= n) return;

    const uint4* __restrict__ base = (const uint4*)xw;

    float acc[8];
    {
        float d = dis[node];
        float d2 = d * d;
        uint4 sv = base[(size_t)node * FQ + q];
        float t[8];
        cvt8(sv, t);
#pragma unroll
        for (int j = 0; j < 8; ++j) acc[j] = d2 * t[j];
    }

    int e0 = row_ptr[node], e1 = row_ptr[node + 1];
    int e = e0;
    for (; e + 4 <= e1; e += 4) {
        unsigned p0 = ep[e + 0], p1 = ep[e + 1], p2 = ep[e + 2], p3 = ep[e + 3];
        uint4 x0 = base[(size_t)(p0 >> 16) * FQ + q];
        uint4 x1 = base[(size_t)(p1 >> 16) * FQ + q];
        uint4 x2 = base[(size_t)(p2 >> 16) * FQ + q];
        uint4 x3 = base[(size_t)(p3 >> 16) * FQ + q];
        h8_acc(x0, (float)(p0 & 0xffffu) * INV_NORM_SCALE, acc);
        h8_acc(x1, (float)(p1 & 0xffffu) * INV_NORM_SCALE, acc);
        h8_acc(x2, (float)(p2 & 0xffffu) * INV_NORM_SCALE, acc);
        h8_acc(x3, (float)(p3 & 0xffffu) * INV_NORM_SCALE, acc);
    }
    for (; e < e1; ++e) {
        unsigned p = ep[e];
        uint4 xv = base[(size_t)(p >> 16) * FQ + q];
        h8_acc(xv, (float)(p & 0xffffu) * INV_NORM_SCALE, acc);
    }

    int fb = q * 8;
    const float4* bb = (const float4*)(bias + fb);
    float4 b0 = bb[0], b1 = bb[1];
    acc[0] += b0.x; acc[1] += b0.y; acc[2] += b0.z; acc[3] += b0.w;
    acc[4] += b1.x; acc[5] += b1.y; acc[6] += b1.z; acc[7] += b1.w;
    if (BN) {
#pragma unroll
        for (int j = 0; j < 8; ++j) {
            acc[j] = fmaxf((acc[j] - m[fb + j]) * rsqrtf(v[fb + j] + BN_EPS) * g[fb + j]
                           + beta[fb + j], 0.f);
        }
    }
    if (F32OUT) {
        float* op = (float*)out + (size_t)node * F + fb;
        *(float4*)(op + 0) = make_float4(acc[0], acc[1], acc[2], acc[3]);
        *(float4*)(op + 4) = make_float4(acc[4], acc[5], acc[6], acc[7]);
    } else {
        __half2 h0 = __floats2half2_rn(acc[0], acc[1]);
        __half2 h1 = __floats2half2_rn(acc[2], acc[3]);
        __half2 h2 = __floats2half2_rn(acc[4], acc[5]);
        __half2 h3 = __floats2half2_rn(acc[6], acc[7]);
        uint4 u = make_uint4(*(unsigned*)&h0, *(unsigned*)&h1,
                             *(unsigned*)&h2, *(unsigned*)&h3);
        ((uint4*)out)[(size_t)node * FQ + q] = u;
    }
}

// ---------------- launch ----------------

extern "C" void kernel_launch(void* const* d_in, const int* in_sizes, int n_in,
                              void* d_out, int out_size, void* d_ws, size_t ws_size,
                              hipStream_t stream) {
    constexpr int IN = 128, H = 96, OUT = 64;

    const float* x   = (const float*)d_in[0];
    const int*   ei  = (const int*)d_in[1];
    const float* ew  = (const float*)d_in[2];
    const float* W1  = (const float*)d_in[3];
    const float* b1  = (const float*)d_in[4];
    const float* W2  = (const float*)d_in[5];
    const float* b2  = (const float*)d_in[6];
    const float* W3  = (const float*)d_in[7];
    const float* b3  = (const float*)d_in[8];
    const float* g1  = (const float*)d_in[9];
    const float* be1 = (const float*)d_in[10];
    const float* m1  = (const float*)d_in[11];
    const float* v1  = (const float*)d_in[12];
    const float* g2  = (const float*)d_in[13];
    const float* be2 = (const float*)d_in[14];
    const float* m2  = (const float*)d_in[15];
    const float* v2  = (const float*)d_in[16];

    const int N = in_sizes[0] / IN;   // 50000
    const int E = in_sizes[2];        // 800000
    const int* row_idx = ei;
    const int* col_idx = ei + E;

    char* ws = (char*)d_ws;
    size_t off = 0;
    auto alloc = [&](size_t bytes) -> void* {
        void* p = ws + off;
        off = (off + bytes + 255) & ~(size_t)255;
        return p;
    };
    unsigned long long* packed = (unsigned long long*)alloc((size_t)N * 8);
    float*     dis     = (float*)alloc((size_t)N * 4);
    int*       row_ptr = (int*)alloc((size_t)(N + 1) * 4);
    int*       bsum    = (int*)alloc(256 * 4);
    int*       rank    = (int*)alloc((size_t)E * 4);
    unsigned*  ep      = (unsigned*)alloc((size_t)E * 4);
    _Float16*  w2h     = (_Float16*)alloc((size_t)H * H * 2);
    _Float16*  w3h     = (_Float16*)alloc((size_t)OUT * H * 2);
    _Float16*  bufA    = (_Float16*)alloc((size_t)N * H * 2);   // gemm out
    _Float16*  bufB    = (_Float16*)alloc((size_t)N * H * 2);   // aggr out
    (void)ws_size; (void)n_in; (void)out_size;

    constexpr int W2N4 = H * H / 4, W3N4 = OUT * H / 4;   // 2304 + 1536 = 3840
    const int NB = (N + 255) / 256;          // 196 (<= 256 for scans)
    const int DEG1024 = (E + 1023) / 1024;   // 782
    const int GG = (N / 16 + 3) / 4;         // 782: 64 nodes/block
    const int PAIR = (DEG1024 > GG) ? DEG1024 : GG;   // 782
    const int CVT_B = (W2N4 + W3N4 + 255) / 256;      // 15

    hipMemsetAsync(packed, 0, (size_t)N * 8, stream);
    k_mega<<<2 * PAIR + CVT_B, 256, 0, stream>>>(
        col_idx, ew, packed, rank, E, PAIR,
        x, W1, bufA, N, W2, W3, w2h, w3h, W2N4, W3N4);
    k_scan1<<<NB, 256, 0, stream>>>(packed, bsum, dis, N);
    k_scan23<<<NB, 256, 0, stream>>>(packed, bsum, row_ptr, N, E, NB);
    k_fill<<<(E + 255) / 256, 256, 0, stream>>>(row_idx, col_idx, ew, dis,
                                                row_ptr, rank, ep, E);

    const int GA96 = ((size_t)N * (H / 8) + 255) / 256;
    const int GA64 = ((size_t)N * (OUT / 8) + 255) / 256;

    // layer 1 aggregation (gemm1 ran inside k_mega)
    k_aggr<H, true, false><<<GA96, 256, 0, stream>>>(
        bufA, row_ptr, ep, dis, b1, g1, be1, m1, v1, bufB, N);

    // layer 2
    k_gemm<H, H><<<GG, 256, 0, stream>>>(bufB, w2h, bufA, N);
    k_aggr<H, true, false><<<GA96, 256, 0, stream>>>(
        bufA, row_ptr, ep, dis, b2, g2, be2, m2, v2, bufB, N);

    // layer 3
    k_gemm<H, OUT><<<GG, 256, 0, stream>>>(bufB, w3h, bufA, N);
    k_aggr<OUT, false, true><<<GA64, 256, 0, stream>>>(
        bufA, row_ptr, ep, dis, b3, nullptr, nullptr, nullptr, nullptr, d_out, N);
}